// Round 11
// baseline (90.027 us; speedup 1.0000x reference)
//
#include <hip/hip_runtime.h>

// Problem dims (fixed by reference)
constexpr int T = 64, B = 8, A = 3, S = 400, V = 50000, N_OOV = 400;
constexpr int V_EXT  = V + N_OOV;      // 50400
constexpr int NSUB   = 6;              // slices per (t,b): 33600 B, 64B-aligned
constexpr int C_SUB  = V_EXT / NSUB;   // 8400 floats per slice
constexpr int C4_SUB = C_SUB / 4;      // 2100 float4 per slice
constexpr int V4     = V / 4;          // 12500 float4 of base vocab
constexpr int NTHR   = 512;
constexpr int FULL_K = C4_SUB / NTHR;  // 4 full strides (+52-thread tail)
constexpr int NSC    = 3;              // ceil(A*S / NTHR)

// ZERO-LDS A/B probe of the R7/R8 geometry. One block per (t,b,slice):
//   1) load scatter entries (idx + weight) -- needed only at the end
//   2) pure stream: out = coef*vp (4 batched float4 loads, one basic block)
//   3) ONE __syncthreads (vmcnt(0) drain: all block stores visible in L2)
//   4) ~200 global atomicAdds filtered to this block's own slice (L2-hot)
// No LDS, no zero phase, no extra barriers -- the stream is structurally
// identical to a copy kernel. Decisive test of "LDS machinery vs 4.2TB/s wall".
__global__ __launch_bounds__(NTHR) void pg_nolds_kernel(
    const int*   __restrict__ article,        // [S,B,A]
    const float* __restrict__ vocab_probs,    // [T,B,V]
    const float* __restrict__ gen_probs,      // [T,B,A]
    const float* __restrict__ agentwise_attn, // [T,B,A,S]
    const float* __restrict__ agent_attn,     // [T,B,A]
    float*       __restrict__ out)            // [T,B,V_EXT]
{
    const int bid = blockIdx.x;
    const int tb  = bid / NSUB;                // t*B + b
    const int sub = bid - tb * NSUB;
    const int b   = tb % B;
    const int tid = threadIdx.x;

    // per-(t,b) scalars
    float coef = 0.f;
    float cw[A];
#pragma unroll
    for (int a = 0; a < A; ++a) {
        const float aa = agent_attn[tb * A + a];
        const float g  = gen_probs[tb * A + a];
        coef += aa * g;
        cw[a] = aa * (1.f - g);
    }

    // scatter entries (used after the stream; compiler may schedule freely)
    int   sidx[NSC];
    float sw[NSC];
    const float* aw = agentwise_attn + (size_t)tb * A * S;   // flat [a*S+s]
#pragma unroll
    for (int j = 0; j < NSC; ++j) {
        const int i2 = tid + j * NTHR;
        sidx[j] = -1; sw[j] = 0.f;
        if (i2 < A * S) {
            const int a = (i2 >= 2 * S) ? 2 : (i2 >= S ? 1 : 0);
            const int s = i2 - a * S;
            sidx[j] = article[(s * B + b) * A + a];
            sw[j]   = cw[a] * aw[i2];
        }
    }

    // pure stream: 4 batched loads (+tail), fma, store -- one basic block
    const float4* vp4  = reinterpret_cast<const float4*>(vocab_probs + (size_t)tb * V);
    float4*       out4 = reinterpret_cast<float4*>(out + (size_t)tb * V_EXT);
    const int base = sub * C4_SUB;
    const int i0   = base + tid;

    float4 v[FULL_K];
#pragma unroll
    for (int k = 0; k < FULL_K; ++k) {
        const int i  = i0 + k * NTHR;
        const int ic = (i < V4) ? i : (V4 - 1);   // clamp (only slice 5 mixes)
        v[k] = vp4[ic];
    }
    const int  it       = i0 + FULL_K * NTHR;
    const bool has_tail = (it < base + C4_SUB);   // 52 threads
    float4 vt = make_float4(0.f, 0.f, 0.f, 0.f);
    if (has_tail) vt = vp4[(it < V4) ? it : (V4 - 1)];

#pragma unroll
    for (int k = 0; k < FULL_K; ++k) {
        const int i = i0 + k * NTHR;
        float4 r = make_float4(0.f, 0.f, 0.f, 0.f);
        if (i < V4) {
            r.x = coef * v[k].x;  r.y = coef * v[k].y;
            r.z = coef * v[k].z;  r.w = coef * v[k].w;
        }
        out4[i] = r;
    }
    if (has_tail) {
        float4 r = make_float4(0.f, 0.f, 0.f, 0.f);
        if (it < V4) {
            r.x = coef * vt.x;  r.y = coef * vt.y;
            r.z = coef * vt.z;  r.w = coef * vt.w;
        }
        out4[it] = r;
    }

    // one drain: all block stores visible in this XCD's L2 before atomics
    __syncthreads();

    // global-atomic scatter into this block's own (L2-hot) slice
    const int lo = sub * C_SUB;
    const int hi = lo + C_SUB;
    float* outp = out + (size_t)tb * V_EXT;
#pragma unroll
    for (int j = 0; j < NSC; ++j) {
        if (sidx[j] >= lo && sidx[j] < hi)
            atomicAdd(outp + sidx[j], sw[j]);
    }
}

extern "C" void kernel_launch(void* const* d_in, const int* in_sizes, int n_in,
                              void* d_out, int out_size, void* d_ws, size_t ws_size,
                              hipStream_t stream) {
    const int*   article        = (const int*)  d_in[0]; // [S,B,A]
    const float* vocab_probs    = (const float*)d_in[1]; // [T,B,V]
    const float* gen_probs      = (const float*)d_in[2]; // [T,B,A]
    const float* agentwise_attn = (const float*)d_in[3]; // [T,B,A,S]
    const float* agent_attn     = (const float*)d_in[4]; // [T,B,A]
    float*       out            = (float*)d_out;         // [T,B,V_EXT]

    pg_nolds_kernel<<<dim3(T * B * NSUB), dim3(NTHR), 0, stream>>>(
        article, vocab_probs, gen_probs, agentwise_attn, agent_attn, out);
}

// Round 12
// 34.998 us; speedup vs baseline: 2.5724x; 2.5724x over previous
//
#include <hip/hip_runtime.h>

// Problem dims (fixed by reference)
constexpr int T = 64, B = 8, A = 3, S = 400, V = 50000, N_OOV = 400;
constexpr int V_EXT  = V + N_OOV;      // 50400
constexpr int NSUB   = 6;              // slices per (t,b): 33.6 KB LDS -> 4 blocks/CU
constexpr int C_SUB  = V_EXT / NSUB;   // 8400 floats per slice
constexpr int C4_SUB = C_SUB / 4;      // 2100 float4 per slice
constexpr int V4     = V / 4;          // 12500 float4 of base vocab
constexpr int NTHR   = 512;
constexpr int FULL_K = C4_SUB / NTHR;  // 4 full strides (+52 tail)
constexpr int NSC    = 3;              // ceil(A*S / NTHR) scatter entries/thread
constexpr int NWG    = T * B * NSUB;   // 3072
constexpr int NXCD   = 8;
constexpr int WG_PER_XCD = NWG / NXCD; // 384 (exact -> bijective swizzle)

typedef float vfloat4 __attribute__((ext_vector_type(4)));

// Best-measured structure (R7, 37.5us) + bijective XCD swizzle.
// One block per (t,b,slice): LDS accumulator for the scatter, fused
// combine stream with nontemporal stores. Zero-LDS fork (R11) proved the
// LDS path is right: global atomics cost 2.4x. Six structural variants
// land at 37.5-38.7us = ~92% of the mixed-stream L2-traffic ceiling
// (218 MB @ 6.29 TB/s copy ceiling = 34.6us floor).
__global__ __launch_bounds__(NTHR, 8) void pg_nt_kernel(
    const int*   __restrict__ article,        // [S,B,A]
    const float* __restrict__ vocab_probs,    // [T,B,V]
    const float* __restrict__ gen_probs,      // [T,B,A]
    const float* __restrict__ agentwise_attn, // [T,B,A,S]
    const float* __restrict__ agent_attn,     // [T,B,A]
    float*       __restrict__ out)            // [T,B,V_EXT]
{
    __shared__ float acc[C_SUB];               // 33600 B
    // bijective XCD swizzle: each XCD owns a contiguous 1/8 of logical ids
    const int bid = (blockIdx.x & (NXCD - 1)) * WG_PER_XCD + (blockIdx.x >> 3);
    const int tb  = bid / NSUB;                // t*B + b
    const int sub = bid - tb * NSUB;
    const int b   = tb % B;
    const int tid = threadIdx.x;

    // per-(t,b) scalars
    float coef = 0.f;
    float cw[A];
#pragma unroll
    for (int a = 0; a < A; ++a) {
        const float aa = agent_attn[tb * A + a];
        const float g  = gen_probs[tb * A + a];
        coef += aa * g;
        cw[a] = aa * (1.f - g);
    }

    // scatter-entry loads (oldest outstanding vmem)
    int   sidx[NSC];
    float sraw[NSC];
    const float* aw = agentwise_attn + (size_t)tb * A * S;   // flat [a*S+s]
#pragma unroll
    for (int j = 0; j < NSC; ++j) {
        const int i2 = tid + j * NTHR;
        sidx[j] = -1; sraw[j] = 0.f;
        if (i2 < A * S) {
            const int a = (i2 >= 2 * S) ? 2 : (i2 >= S ? 1 : 0);
            const int s = i2 - a * S;
            sidx[j] = article[(s * B + b) * A + a];
            sraw[j] = aw[i2];
        }
    }

    // issue vocab reads
    const float4* vp4  = reinterpret_cast<const float4*>(vocab_probs + (size_t)tb * V);
    vfloat4*      out4 = reinterpret_cast<vfloat4*>(out + (size_t)tb * V_EXT);
    const int base = sub * C4_SUB;
    const int i0   = base + tid;

    float4 v[FULL_K];
#pragma unroll
    for (int k = 0; k < FULL_K; ++k) {
        const int i  = i0 + k * NTHR;
        const int ic = (i < V4) ? i : (V4 - 1);   // clamp (only slice 5 mixes)
        v[k] = vp4[ic];
    }
    const int  it       = i0 + FULL_K * NTHR;
    const bool has_tail = (it < base + C4_SUB);   // 52 threads per block
    float4 vt = make_float4(0.f, 0.f, 0.f, 0.f);
    if (has_tail) vt = vp4[(it < V4) ? it : (V4 - 1)];

    // zero the slice accumulator
    float4* acc4 = reinterpret_cast<float4*>(acc);
    for (int j = tid; j < C4_SUB; j += NTHR)
        acc4[j] = make_float4(0.f, 0.f, 0.f, 0.f);
    __syncthreads();

    // scatter from registers into LDS (filtered to this slice)
    const int lo = sub * C_SUB;
    const int hi = lo + C_SUB;
#pragma unroll
    for (int j = 0; j < NSC; ++j) {
        if (sidx[j] >= lo && sidx[j] < hi) {
            const int i2 = tid + j * NTHR;
            const int a  = (i2 >= 2 * S) ? 2 : (i2 >= S ? 1 : 0);
            atomicAdd(&acc[sidx[j] - lo], cw[a] * sraw[j]);
        }
    }
    __syncthreads();

    // combine + non-temporal coalesced store stream
#pragma unroll
    for (int k = 0; k < FULL_K; ++k) {
        const int i = i0 + k * NTHR;
        float4 r = acc4[i - base];
        if (i < V4) {
            r.x += coef * v[k].x;  r.y += coef * v[k].y;
            r.z += coef * v[k].z;  r.w += coef * v[k].w;
        }
        vfloat4 rr = {r.x, r.y, r.z, r.w};
        __builtin_nontemporal_store(rr, &out4[i]);
    }
    if (has_tail) {
        float4 r = acc4[it - base];
        if (it < V4) {
            r.x += coef * vt.x;  r.y += coef * vt.y;
            r.z += coef * vt.z;  r.w += coef * vt.w;
        }
        vfloat4 rr = {r.x, r.y, r.z, r.w};
        __builtin_nontemporal_store(rr, &out4[it]);
    }
}

extern "C" void kernel_launch(void* const* d_in, const int* in_sizes, int n_in,
                              void* d_out, int out_size, void* d_ws, size_t ws_size,
                              hipStream_t stream) {
    const int*   article        = (const int*)  d_in[0]; // [S,B,A]
    const float* vocab_probs    = (const float*)d_in[1]; // [T,B,V]
    const float* gen_probs      = (const float*)d_in[2]; // [T,B,A]
    const float* agentwise_attn = (const float*)d_in[3]; // [T,B,A,S]
    const float* agent_attn     = (const float*)d_in[4]; // [T,B,A]
    float*       out            = (float*)d_out;         // [T,B,V_EXT]

    pg_nt_kernel<<<dim3(NWG), dim3(NTHR), 0, stream>>>(
        article, vocab_probs, gen_probs, agentwise_attn, agent_attn, out);
}